// Round 9
// baseline (221.831 us; speedup 1.0000x reference)
//
#include <hip/hip_runtime.h>
#include <stdint.h>
#include <math.h>

#define L_DIM 3
#define B_DIM 64
#define P_DIM 225
#define D_DIM 640
#define R_DIM 1800
#define S_DIM 240
#define M_TOT 14400
#define M_PAD 14464             /* 113*128 */
#define N_PAD 2048              /* 8*256 */
#define MT 113
#define NT 8
#define KT 20                   /* 640/32 */
#define BNSCALE 0.99999500003749981f  /* 1/sqrt(1+1e-5) */

typedef __bf16 bf16x8 __attribute__((ext_vector_type(8)));
typedef float f32x4 __attribute__((ext_vector_type(4)));

__device__ __forceinline__ unsigned short f2bf(float f) {
    union { float f; unsigned u; } v; v.f = f;
    unsigned u = v.u;
    unsigned r = (u + 0x7FFFu + ((u >> 16) & 1u)) >> 16;   // RNE
    return (unsigned short)r;
}

// ---------------------------------------------------------------- K0: convert
__global__ __launch_bounds__(256)
void k_convert(const float* __restrict__ pe, const float* __restrict__ per,
               unsigned short* __restrict__ abf, unsigned short* __restrict__ rbf,
               float* __restrict__ rnorm)
{
    const int AROWS = L_DIM * M_PAD;            // 43392
    int wid = (blockIdx.x * 256 + threadIdx.x) >> 6;
    int lane = threadIdx.x & 63;
    const ushort4 z4 = {0, 0, 0, 0};
    if (wid < AROWS) {
        int l = wid / M_PAD, r = wid - l * M_PAD;
        unsigned short* dst = abf + (size_t)wid * D_DIM;
        if (r < M_TOT) {
            const float4* src = (const float4*)(pe + ((size_t)l * M_TOT + r) * D_DIM);
            float ss = 0.f;
            #pragma unroll
            for (int it = 0; it < 3; ++it) {
                int idx = it * 64 + lane;
                if (idx < 160) {
                    float4 v = src[idx];
                    ss += v.x * v.x + v.y * v.y + v.z * v.z + v.w * v.w;
                    ushort4 o;
                    o.x = f2bf(v.x); o.y = f2bf(v.y); o.z = f2bf(v.z); o.w = f2bf(v.w);
                    *(ushort4*)(dst + idx * 4) = o;
                }
            }
            #pragma unroll
            for (int m = 32; m; m >>= 1) ss += __shfl_xor(ss, m);
            if (lane == 0) rnorm[l * M_TOT + r] = rsqrtf(ss);
        } else {
            #pragma unroll
            for (int it = 0; it < 3; ++it) {
                int idx = it * 64 + lane;
                if (idx < 160) *(ushort4*)(dst + idx * 4) = z4;
            }
        }
    } else {
        int w2 = wid - AROWS;
        int l = w2 / N_PAD, r = w2 - l * N_PAD;
        unsigned short* dst = rbf + (size_t)w2 * D_DIM;
        if (r < R_DIM) {
            const float4* src = (const float4*)(per + ((size_t)l * R_DIM + r) * D_DIM);
            #pragma unroll
            for (int it = 0; it < 3; ++it) {
                int idx = it * 64 + lane;
                if (idx < 160) {
                    float4 v = src[idx];
                    ushort4 o;
                    o.x = f2bf(v.x); o.y = f2bf(v.y); o.z = f2bf(v.z); o.w = f2bf(v.w);
                    *(ushort4*)(dst + idx * 4) = o;
                }
            }
        } else {
            #pragma unroll
            for (int it = 0; it < 3; ++it) {
                int idx = it * 64 + lane;
                if (idx < 160) *(ushort4*)(dst + idx * 4) = z4;
            }
        }
    }
}

// ---------------- K1: 128x256, BK=32, triple-buffered, 2 blocks/CU, 1 barrier/tile
// LDS (shorts): A bufs @ t*4096 (8KB each), B bufs @ 12288 + t*8192 (16KB each).
// Packed layout: logical (r,k) -> physical (r>>1, (r&1)*32+k) in [*][64]-short
// rows, 16B-chunk XOR-swizzled by prow&7. Staged via pre-swizzled global src.
#define MFMA(A, B, C) __builtin_amdgcn_mfma_f32_16x16x32_bf16((A), (B), (C), 0, 0, 0)
#define GLL(SRC, DSTOFF)                                                     \
    __builtin_amdgcn_global_load_lds(                                        \
        (const __attribute__((address_space(1))) void*)(SRC),               \
        (__attribute__((address_space(3))) void*)(lds + (DSTOFF)), 16, 0, 0)

__global__ __launch_bounds__(512, 4)
void k_gemm_max(const unsigned short* __restrict__ abf,
                const unsigned short* __restrict__ rbf,
                float* __restrict__ pmax)
{
    __shared__ unsigned short lds[36864];   // 72 KB
    __shared__ float red[4][128];

    // XCD-chunked bijective swizzle: 2712 blocks = 8 XCDs * 339
    int bid = blockIdx.x;
    int v = (bid & 7) * 339 + (bid >> 3);
    int l = v / (MT * NT);
    int rem = v - l * (MT * NT);
    int mt = rem >> 3;
    int nt = rem & 7;

    int tid = threadIdx.x;
    int wid = tid >> 6, lane = tid & 63;
    int wm = wid >> 2;                  // 0..1 -> rows wm*64
    int wn = wid & 3;                   // 0..3 -> cols wn*64
    int lane15 = lane & 15, lg = lane >> 4;

    // staging source (pre-swizzled): lane -> (lpr, c2); logical row/kchunk
    int lpr = lane >> 3;                // physical row in 8-row chunk
    int c2  = (lane & 7) ^ lpr;         // swizzled 16B slot
    int kc  = c2 & 3;                   // k-chunk (8 shorts)
    int rsub = lpr * 2 + (c2 >> 2);     // logical row within 16-row group
    const unsigned short* gA = abf + (size_t)(l * M_PAD + mt * 128) * D_DIM;
    const unsigned short* gB = rbf + (size_t)(l * N_PAD + nt * 256) * D_DIM;
    const unsigned short* pA  = gA + (size_t)(wid * 16 + rsub) * D_DIM + kc * 8;
    const unsigned short* pB0 = gB + (size_t)(wid * 16 + rsub) * D_DIM + kc * 8;
    const unsigned short* pB1 = gB + (size_t)(wid * 16 + 128 + rsub) * D_DIM + kc * 8;

    // frag read offsets (shorts): chunk = ((r&1)*4+lg) ^ (prow&7), mi/nj-invariant
    int pcom = (((lane15 & 1) << 2) + lg) ^ ((lane15 >> 1) & 7);
    int aoff = (wm * 32 + (lane15 >> 1)) * 64 + pcom * 8;   // + mi*512
    int boff = (wn * 32 + (lane15 >> 1)) * 64 + pcom * 8;   // + nj*512

    f32x4 acc[4][4];
    #pragma unroll
    for (int mi = 0; mi < 4; ++mi)
        #pragma unroll
        for (int nj = 0; nj < 4; ++nj)
            acc[mi][nj] = f32x4{0.f, 0.f, 0.f, 0.f};

    // prologue: stage tiles 0 and 1
    GLL(pA, wid * 512);
    GLL(pB0, 12288 + wid * 512);
    GLL(pB1, 12288 + (8 + wid) * 512);
    GLL(pA + 32, 4096 + wid * 512);
    GLL(pB0 + 32, 12288 + 8192 + wid * 512);
    GLL(pB1 + 32, 12288 + 8192 + (8 + wid) * 512);
    asm volatile("s_waitcnt vmcnt(3)" ::: "memory");
    __builtin_amdgcn_s_barrier();

    int cur = 0;
    for (int t = 0; t < KT; ++t) {
        int wr = cur + 2; if (wr >= 3) wr -= 3;
        int aB = cur * 4096;
        int bB = 12288 + cur * 8192;

        // frag reads for tile t (valid: guaranteed by previous vmcnt+barrier)
        bf16x8 a[4], b[4];
        #pragma unroll
        for (int mi = 0; mi < 4; ++mi)
            a[mi] = *(const bf16x8*)(lds + aB + aoff + mi * 512);
        #pragma unroll
        for (int nj = 0; nj < 4; ++nj)
            b[nj] = *(const bf16x8*)(lds + bB + boff + nj * 512);

        // stage tile t+2 (clamped dummy for the tail; never hits a live buffer)
        int koff = (t + 2 < KT ? t + 2 : KT - 1) * 32;
        GLL(pA + koff, wr * 4096 + wid * 512);
        GLL(pB0 + koff, 12288 + wr * 8192 + wid * 512);
        GLL(pB1 + koff, 12288 + wr * 8192 + (8 + wid) * 512);
        asm volatile("s_waitcnt vmcnt(3)" ::: "memory");
        __builtin_amdgcn_s_barrier();

        __builtin_amdgcn_s_setprio(1);
        #pragma unroll
        for (int mi = 0; mi < 4; ++mi)
            #pragma unroll
            for (int nj = 0; nj < 4; ++nj)
                acc[mi][nj] = MFMA(a[mi], b[nj], acc[mi][nj]);
        __builtin_amdgcn_s_setprio(0);

        cur = (cur == 2) ? 0 : cur + 1;
    }

    __syncthreads();

    // fused epilogue: mask cols >= 1800, rowmax over the block's 256 cols.
    // C/D layout: col = lane&15, row = (lane>>4)*4 + reg  [m89-verified]
    int colbase = nt * 256 + wn * 64 + lane15;
    #pragma unroll
    for (int mi = 0; mi < 4; ++mi) {
        float t[4] = {-__builtin_inff(), -__builtin_inff(),
                      -__builtin_inff(), -__builtin_inff()};
        #pragma unroll
        for (int nj = 0; nj < 4; ++nj) {
            if (colbase + nj * 16 < R_DIM) {
                #pragma unroll
                for (int r = 0; r < 4; ++r) t[r] = fmaxf(t[r], acc[mi][nj][r]);
            }
        }
        #pragma unroll
        for (int m = 1; m <= 8; m <<= 1) {
            #pragma unroll
            for (int r = 0; r < 4; ++r) t[r] = fmaxf(t[r], __shfl_xor(t[r], m));
        }
        if (lane15 == 0) {
            int rb = wm * 64 + mi * 16 + lg * 4;
            #pragma unroll
            for (int r = 0; r < 4; ++r) red[wn][rb + r] = t[r];
        }
    }
    __syncthreads();
    if (tid < 128) {
        float vmx = fmaxf(fmaxf(red[0][tid], red[1][tid]),
                          fmaxf(red[2][tid], red[3][tid]));
        pmax[((size_t)l * NT + nt) * M_PAD + mt * 128 + tid] = vmx;
    }
}

// --------------------- K3: small net + fused combine + fused resize (512 thr)
__device__ __forceinline__ float block_sum8(float v, volatile float* scratch) {
    #pragma unroll
    for (int m = 32; m; m >>= 1) v += __shfl_xor(v, m);
    int w = threadIdx.x >> 6;
    __syncthreads();
    if ((threadIdx.x & 63) == 0) scratch[w] = v;
    __syncthreads();
    float r = 0.f;
    #pragma unroll
    for (int i = 0; i < 8; ++i) r += scratch[i];
    return r;
}
__device__ __forceinline__ float block_max8(float v, volatile float* scratch) {
    #pragma unroll
    for (int m = 32; m; m >>= 1) v = fmaxf(v, __shfl_xor(v, m));
    int w = threadIdx.x >> 6;
    __syncthreads();
    if ((threadIdx.x & 63) == 0) scratch[w] = v;
    __syncthreads();
    float r = scratch[0];
    #pragma unroll
    for (int i = 1; i < 8; ++i) r = fmaxf(r, scratch[i]);
    return r;
}

__global__ __launch_bounds__(512)
void k_small(const float* __restrict__ ie, const float* __restrict__ te,
             const float* __restrict__ ier,
             const float* __restrict__ a_w1, const float* __restrict__ a_w2,
             const float* __restrict__ r_w1, const float* __restrict__ r_b1,
             const float* __restrict__ r_g2, const float* __restrict__ r_be2,
             const float* __restrict__ r_w2, const float* __restrict__ r_b2,
             const float* __restrict__ r_g3, const float* __restrict__ r_be3,
             const float* __restrict__ r_w3, const float* __restrict__ r_b3,
             const float* __restrict__ h_w1, const float* __restrict__ h_b1,
             const float* __restrict__ h_g2, const float* __restrict__ h_be2,
             const float* __restrict__ h_w2, const float* __restrict__ h_b2,
             const float* __restrict__ h_g3, const float* __restrict__ h_be3,
             const float* __restrict__ h_w3, const float* __restrict__ h_b3,
             const float* __restrict__ pmax, const float* __restrict__ rnorm,
             float* __restrict__ out_score, float* __restrict__ outh)
{
    int b = blockIdx.x, tid = threadIdx.x;
    __shared__ float x[D_DIM];
    __shared__ float h1[160];
    __shared__ float dif[D_DIM];
    __shared__ float z1[128];
    __shared__ float z2[64];
    __shared__ float hol[P_DIM];
    __shared__ float rcp[P_DIM];
    __shared__ float heatl[256];
    __shared__ float scratch[8];

    for (int i = tid; i < D_DIM; i += 512) x[i] = ie[b * D_DIM + i];
    __syncthreads();

    float ss = 0.f, d0 = 0.f, d1 = 0.f;
    for (int i = tid; i < D_DIM; i += 512) {
        float v = x[i];
        ss += v * v;
        d0 += v * te[i];
        d1 += v * te[D_DIM + i];
    }
    float ssum = block_sum8(ss, scratch);
    float dd0 = block_sum8(d0, scratch);
    float dd1 = block_sum8(d1, scratch);
    float tscore = 1.f / (1.f + expf(100.f * rsqrtf(ssum) * (dd0 - dd1)));

    for (int o = tid; o < 160; o += 512) {
        const float* w = a_w1 + (size_t)o * D_DIM;
        float s0 = 0, s1 = 0, s2 = 0, s3 = 0;
        for (int d = 0; d < D_DIM; d += 4) {
            s0 += x[d] * w[d]; s1 += x[d + 1] * w[d + 1];
            s2 += x[d + 2] * w[d + 2]; s3 += x[d + 3] * w[d + 3];
        }
        h1[o] = fmaxf((s0 + s1) + (s2 + s3), 0.f);
    }
    __syncthreads();
    for (int d = tid; d < D_DIM; d += 512) {
        const float* w = a_w2 + (size_t)d * 160;
        float s0 = 0, s1 = 0, s2 = 0, s3 = 0;
        for (int o = 0; o < 160; o += 4) {
            s0 += h1[o] * w[o]; s1 += h1[o + 1] * w[o + 1];
            s2 += h1[o + 2] * w[o + 2]; s3 += h1[o + 3] * w[o + 3];
        }
        dif[d] = ier[d] - fmaxf((s0 + s1) + (s2 + s3), 0.f);
    }
    __syncthreads();

    for (int o = tid; o < 128; o += 512) {
        const float* w = r_w1 + (size_t)o * D_DIM;
        float s0 = 0, s1 = 0, s2 = 0, s3 = 0;
        for (int d = 0; d < D_DIM; d += 4) {
            s0 += dif[d] * w[d]; s1 += dif[d + 1] * w[d + 1];
            s2 += dif[d + 2] * w[d + 2]; s3 += dif[d + 3] * w[d + 3];
        }
        float s = (s0 + s1) + (s2 + s3) + r_b1[o];
        z1[o] = fmaxf(s, 0.f) * (r_g2[o] * BNSCALE) + r_be2[o];
    }
    __syncthreads();
    for (int o = tid; o < 64; o += 512) {
        const float* w = r_w2 + (size_t)o * 128;
        float s = r_b2[o];
        for (int d = 0; d < 128; ++d) s += z1[d] * w[d];
        z2[o] = fmaxf(s, 0.f) * (r_g3[o] * BNSCALE) + r_be3[o];
    }
    __syncthreads();
    float sp = (tid < 64) ? z2[tid] * r_w3[tid] : 0.f;
    float irs = 1.f / (1.f + expf(-(block_sum8(sp, scratch) + r_b3[0])));

    float fgp = -__builtin_inff();
    float base = tscore + irs;
    for (int p = tid; p < P_DIM; p += 512) {
        int r = b * P_DIM + p;
        float s = 0.f;
        #pragma unroll
        for (int l = 0; l < L_DIM; ++l) {
            float m = -__builtin_inff();
            #pragma unroll
            for (int t = 0; t < NT; ++t)
                m = fmaxf(m, pmax[((size_t)l * NT + t) * M_PAD + r]);
            s += m * rnorm[l * M_TOT + r];
        }
        float pv = (3.0f - s) / 6.0f;
        fgp = fmaxf(fgp, pv);
        float h = base + pv;
        hol[p] = h;
        rcp[p] = 1.f / h;
    }
    float fg = block_max8(fgp, scratch);

    for (int o = tid; o < 128; o += 512) {
        const float* w = h_w1 + (size_t)o * P_DIM;
        float s = h_b1[o];
        for (int d = 0; d < P_DIM; ++d) s += hol[d] * w[d];
        z1[o] = fmaxf(s, 0.f) * (h_g2[o] * BNSCALE) + h_be2[o];
    }
    __syncthreads();
    for (int o = tid; o < 64; o += 512) {
        const float* w = h_w2 + (size_t)o * 128;
        float s = h_b2[o];
        for (int d = 0; d < 128; ++d) s += z1[d] * w[d];
        z2[o] = fmaxf(s, 0.f) * (h_g3[o] * BNSCALE) + h_be3[o];
    }
    __syncthreads();
    float sp2 = (tid < 64) ? z2[tid] * h_w3[tid] : 0.f;
    float hl_in = block_sum8(sp2, scratch) + h_b3[0];
    if (tid == 0) {
        float hl = 1.f / (1.f + expf(-hl_in));
        out_score[b] = (hl + fg) * 0.5f;
    }

    if (tid < 256) {
        int r = tid >> 4, c = tid & 15;
        float s = 0.f, cnt = 0.f;
        #pragma unroll
        for (int di = -1; di <= 0; ++di) {
            int i = r + di;
            if (i < 0 || i > 14) continue;
            #pragma unroll
            for (int dj = -1; dj <= 0; ++dj) {
                int j = c + dj;
                if (j < 0 || j > 14) continue;
                s += rcp[i * 15 + j];
                cnt += 1.f;
            }
        }
        heatl[tid] = cnt / s;
    }
    __syncthreads();

    // fused resize: jax bilinear 16->240 == clamped half-pixel, s=(o-7)/15
    float* dst = outh + (size_t)b * (S_DIM * S_DIM);
    for (int px = tid; px < S_DIM * S_DIM; px += 512) {
        int y = px / S_DIM, xc = px - y * S_DIM;
        float sy = fminf(fmaxf((y - 7) * (1.0f / 15.0f), 0.f), 15.f);
        float sx = fminf(fmaxf((xc - 7) * (1.0f / 15.0f), 0.f), 15.f);
        int y0 = (int)sy, x0 = (int)sx;
        int y1 = min(y0 + 1, 15), x1 = min(x0 + 1, 15);
        float fy = sy - (float)y0, fx = sx - (float)x0;
        float v00 = heatl[y0 * 16 + x0], v01 = heatl[y0 * 16 + x1];
        float v10 = heatl[y1 * 16 + x0], v11 = heatl[y1 * 16 + x1];
        float vv = (1.f - fy) * ((1.f - fx) * v00 + fx * v01)
                 + fy * ((1.f - fx) * v10 + fx * v11);
        dst[px] = vv;
    }
}

// ---------------------------------------------------------------- launcher
extern "C" void kernel_launch(void* const* d_in, const int* in_sizes, int n_in,
                              void* d_out, int out_size, void* d_ws, size_t ws_size,
                              hipStream_t stream)
{
    (void)in_sizes; (void)n_in; (void)out_size; (void)ws_size;
    const float* image_embeds = (const float*)d_in[1];
    const float* patch_embeds = (const float*)d_in[2];
    const float* text_embeds  = (const float*)d_in[3];
    const float* ier          = (const float*)d_in[4];
    const float* per          = (const float*)d_in[5];
    const float* a_w1 = (const float*)d_in[6];
    const float* a_w2 = (const float*)d_in[7];
    const float* r_w1 = (const float*)d_in[8];
    const float* r_b1 = (const float*)d_in[9];
    const float* r_g2 = (const float*)d_in[10];
    const float* r_be2 = (const float*)d_in[11];
    const float* r_w2 = (const float*)d_in[12];
    const float* r_b2 = (const float*)d_in[13];
    const float* r_g3 = (const float*)d_in[14];
    const float* r_be3 = (const float*)d_in[15];
    const float* r_w3 = (const float*)d_in[16];
    const float* r_b3 = (const float*)d_in[17];
    const float* h_w1 = (const float*)d_in[18];
    const float* h_b1 = (const float*)d_in[19];
    const float* h_g2 = (const float*)d_in[20];
    const float* h_be2 = (const float*)d_in[21];
    const float* h_w2 = (const float*)d_in[22];
    const float* h_b2 = (const float*)d_in[23];
    const float* h_g3 = (const float*)d_in[24];
    const float* h_be3 = (const float*)d_in[25];
    const float* h_w3 = (const float*)d_in[26];
    const float* h_b3 = (const float*)d_in[27];

    char* ws = (char*)d_ws;
    size_t off = 0;
    auto take = [&](size_t bytes) -> void* {
        void* p = ws + off;
        off += (bytes + 255) & ~(size_t)255;
        return p;
    };
    float* rnorm = (float*)take((size_t)L_DIM * M_TOT * 4);            // 173 KB
    float* pmax  = (float*)take((size_t)L_DIM * NT * M_PAD * 4);       // 1.4 MB
    unsigned short* abf = (unsigned short*)take((size_t)L_DIM * M_PAD * D_DIM * 2); // 55.6 MB
    unsigned short* rbf = (unsigned short*)take((size_t)L_DIM * N_PAD * D_DIM * 2); //  7.9 MB

    float* out_f = (float*)d_out;  // [64] final_score || [64*240*240] hmap, f32

    k_convert<<<dim3((L_DIM * M_PAD + L_DIM * N_PAD) / 4), dim3(256), 0, stream>>>(
        patch_embeds, per, abf, rbf, rnorm);
    k_gemm_max<<<dim3(L_DIM * MT * NT), dim3(512), 0, stream>>>(abf, rbf, pmax);
    k_small<<<dim3(B_DIM), dim3(512), 0, stream>>>(image_embeds, text_embeds, ier,
        a_w1, a_w2, r_w1, r_b1, r_g2, r_be2, r_w2, r_b2, r_g3, r_be3, r_w3, r_b3,
        h_w1, h_b1, h_g2, h_be2, h_w2, h_b2, h_g3, h_be3, h_w3, h_b3,
        pmax, rnorm, out_f, out_f + B_DIM);
}

// Round 10
// 219.700 us; speedup vs baseline: 1.0097x; 1.0097x over previous
//
#include <hip/hip_runtime.h>
#include <stdint.h>
#include <math.h>

#define L_DIM 3
#define B_DIM 64
#define P_DIM 225
#define D_DIM 640
#define R_DIM 1800
#define S_DIM 240
#define M_TOT 14400
#define M_PAD 14592             /* 57*256 */
#define N_PAD 1920              /* 15*128 */
#define MT 57
#define NT 15
#define KT 10                   /* 640/64 */
#define BNSCALE 0.99999500003749981f  /* 1/sqrt(1+1e-5) */

typedef __bf16 bf16x8 __attribute__((ext_vector_type(8)));
typedef float f32x4 __attribute__((ext_vector_type(4)));

__device__ __forceinline__ unsigned short f2bf(float f) {
    union { float f; unsigned u; } v; v.f = f;
    unsigned u = v.u;
    unsigned r = (u + 0x7FFFu + ((u >> 16) & 1u)) >> 16;   // RNE
    return (unsigned short)r;
}

// ---------------------------------------------------------------- K0: convert
__global__ __launch_bounds__(256)
void k_convert(const float* __restrict__ pe, const float* __restrict__ per,
               unsigned short* __restrict__ abf, unsigned short* __restrict__ rbf,
               float* __restrict__ rnorm)
{
    const int AROWS = L_DIM * M_PAD;            // 43776
    int wid = (blockIdx.x * 256 + threadIdx.x) >> 6;
    int lane = threadIdx.x & 63;
    const ushort4 z4 = {0, 0, 0, 0};
    if (wid < AROWS) {
        int l = wid / M_PAD, r = wid - l * M_PAD;
        unsigned short* dst = abf + (size_t)wid * D_DIM;
        if (r < M_TOT) {
            const float4* src = (const float4*)(pe + ((size_t)l * M_TOT + r) * D_DIM);
            float ss = 0.f;
            #pragma unroll
            for (int it = 0; it < 3; ++it) {
                int idx = it * 64 + lane;
                if (idx < 160) {
                    float4 v = src[idx];
                    ss += v.x * v.x + v.y * v.y + v.z * v.z + v.w * v.w;
                    ushort4 o;
                    o.x = f2bf(v.x); o.y = f2bf(v.y); o.z = f2bf(v.z); o.w = f2bf(v.w);
                    *(ushort4*)(dst + idx * 4) = o;
                }
            }
            #pragma unroll
            for (int m = 32; m; m >>= 1) ss += __shfl_xor(ss, m);
            if (lane == 0) rnorm[l * M_TOT + r] = rsqrtf(ss);
        } else {
            #pragma unroll
            for (int it = 0; it < 3; ++it) {
                int idx = it * 64 + lane;
                if (idx < 160) *(ushort4*)(dst + idx * 4) = z4;
            }
        }
    } else {
        int w2 = wid - AROWS;
        int l = w2 / N_PAD, r = w2 - l * N_PAD;
        unsigned short* dst = rbf + (size_t)w2 * D_DIM;
        if (r < R_DIM) {
            const float4* src = (const float4*)(per + ((size_t)l * R_DIM + r) * D_DIM);
            #pragma unroll
            for (int it = 0; it < 3; ++it) {
                int idx = it * 64 + lane;
                if (idx < 160) {
                    float4 v = src[idx];
                    ushort4 o;
                    o.x = f2bf(v.x); o.y = f2bf(v.y); o.z = f2bf(v.z); o.w = f2bf(v.w);
                    *(ushort4*)(dst + idx * 4) = o;
                }
            }
        } else {
            #pragma unroll
            for (int it = 0; it < 3; ++it) {
                int idx = it * 64 + lane;
                if (idx < 160) *(ushort4*)(dst + idx * 4) = z4;
            }
        }
    }
}

// -------- K1: 256x128 tile, BK=64, double-buffered, ONE vmcnt(0)+barrier/tile
// Loads for tile t+1 issue right after barrier(t) and are waited at
// barrier(t+1): a full 32-MFMA cluster of overlap; vmcnt(0) is ~free.
// WAR: GLL(iter t+1) writes buf(t), whose reads all completed before
// barrier(t+1).  Swizzled staging/reads identical to proven R6 kernel.
#define MFMA(A, B, C) __builtin_amdgcn_mfma_f32_16x16x32_bf16((A), (B), (C), 0, 0, 0)
#define GLL(SRC, DSTOFF)                                                     \
    __builtin_amdgcn_global_load_lds(                                        \
        (const __attribute__((address_space(1))) void*)(SRC),               \
        (__attribute__((address_space(3))) void*)(lds + (DSTOFF)), 16, 0, 0)

__global__ __launch_bounds__(512, 1)
void k_gemm_max(const unsigned short* __restrict__ abf,
                const unsigned short* __restrict__ rbf,
                float* __restrict__ pmax)
{
    __shared__ unsigned short lds[49152];   // A: 2x32KB @0; B: 2x16KB @32768
    __shared__ float red[2][256];

    // bijective XCD-chunked swizzle: 2565 = 5*321 + 3*320
    int bid = blockIdx.x;
    int xcd = bid & 7, idx = bid >> 3;
    int v = (xcd < 5 ? xcd * 321 : 5 * 321 + (xcd - 5) * 320) + idx;
    int l = v / (MT * NT);
    int rem = v - l * (MT * NT);
    int mt = rem / NT;
    int nt = rem - mt * NT;

    int tid = threadIdx.x;
    int wid = tid >> 6, lane = tid & 63;
    int wm = wid >> 1;                      // 0..3 -> rows wm*64
    int wn = wid & 1;                       // 0..1 -> cols wn*64
    int lane15 = lane & 15, lg = lane >> 4;
    int sA = lane15 & 7;
    int sw0 = (lg ^ sA) << 3;               // ks=0 swizzled k-chunk (shorts)
    int sw1 = ((4 + lg) ^ sA) << 3;         // ks=1
    int arow0 = wm * 64 + lane15;
    int brow0 = wn * 64 + lane15;

    // staging source (pre-swizzled so linear LDS dest = swizzled layout)
    int rowc = lane >> 3;
    int scol = ((lane & 7) ^ rowc) << 3;
    const unsigned short* gA = abf + (size_t)(l * M_PAD + mt * 256) * D_DIM;
    const unsigned short* gB = rbf + (size_t)(l * N_PAD + nt * 128) * D_DIM;
    // A: 32 chunks (8 rows each), wave stages {wid, 8+wid, 16+wid, 24+wid}
    // B: 16 chunks, wave stages {wid, 8+wid}
    const unsigned short* pA0 = gA + (size_t)(wid * 8 + rowc) * D_DIM + scol;
    const unsigned short* pA1 = gA + (size_t)(64 + wid * 8 + rowc) * D_DIM + scol;
    const unsigned short* pA2 = gA + (size_t)(128 + wid * 8 + rowc) * D_DIM + scol;
    const unsigned short* pA3 = gA + (size_t)(192 + wid * 8 + rowc) * D_DIM + scol;
    const unsigned short* pB0 = gB + (size_t)(wid * 8 + rowc) * D_DIM + scol;
    const unsigned short* pB1 = gB + (size_t)(64 + wid * 8 + rowc) * D_DIM + scol;

    f32x4 acc[4][4];
    #pragma unroll
    for (int mi = 0; mi < 4; ++mi)
        #pragma unroll
        for (int nj = 0; nj < 4; ++nj)
            acc[mi][nj] = f32x4{0.f, 0.f, 0.f, 0.f};

    // prologue: stage K-tile 0 into buf0 (drained by loop's first vmcnt+barrier)
    GLL(pA0, wid * 512);
    GLL(pA1, (8 + wid) * 512);
    GLL(pA2, (16 + wid) * 512);
    GLL(pA3, (24 + wid) * 512);
    GLL(pB0, 32768 + wid * 512);
    GLL(pB1, 32768 + (8 + wid) * 512);

    int buf = 0;
    for (int t = 0; t < KT; ++t) {
        int aB = buf * 16384;
        int bB = 32768 + buf * 8192;

        asm volatile("s_waitcnt vmcnt(0)" ::: "memory");
        __builtin_amdgcn_s_barrier();

        bf16x8 a[4][2], b[4][2];
        #pragma unroll
        for (int mi = 0; mi < 4; ++mi) {
            a[mi][0] = *(const bf16x8*)(lds + aB + (arow0 + mi * 16) * 64 + sw0);
            a[mi][1] = *(const bf16x8*)(lds + aB + (arow0 + mi * 16) * 64 + sw1);
        }
        #pragma unroll
        for (int nj = 0; nj < 4; ++nj) {
            b[nj][0] = *(const bf16x8*)(lds + bB + (brow0 + nj * 16) * 64 + sw0);
            b[nj][1] = *(const bf16x8*)(lds + bB + (brow0 + nj * 16) * 64 + sw1);
        }

        if (t + 1 < KT) {                    // stage tile t+1 into other buffer
            int ko = (t + 1) * 64;
            int oaB = (buf ^ 1) * 16384;
            int obB = 32768 + (buf ^ 1) * 8192;
            GLL(pA0 + ko, oaB + wid * 512);
            GLL(pA1 + ko, oaB + (8 + wid) * 512);
            GLL(pA2 + ko, oaB + (16 + wid) * 512);
            GLL(pA3 + ko, oaB + (24 + wid) * 512);
            GLL(pB0 + ko, obB + wid * 512);
            GLL(pB1 + ko, obB + (8 + wid) * 512);
        }

        __builtin_amdgcn_s_setprio(1);
        #pragma unroll
        for (int ks = 0; ks < 2; ++ks)
            #pragma unroll
            for (int mi = 0; mi < 4; ++mi)
                #pragma unroll
                for (int nj = 0; nj < 4; ++nj)
                    acc[mi][nj] = MFMA(a[mi][ks], b[nj][ks], acc[mi][nj]);
        __builtin_amdgcn_s_setprio(0);

        buf ^= 1;
    }

    __syncthreads();

    // fused epilogue: mask cols >= 1800, rowmax over the block's 128 cols.
    // C/D layout: col = lane&15, row = (lane>>4)*4 + reg  [m89-verified]
    int colbase = nt * 128 + wn * 64 + lane15;
    #pragma unroll
    for (int mi = 0; mi < 4; ++mi) {
        float t[4] = {-__builtin_inff(), -__builtin_inff(),
                      -__builtin_inff(), -__builtin_inff()};
        #pragma unroll
        for (int nj = 0; nj < 4; ++nj) {
            if (colbase + nj * 16 < R_DIM) {
                #pragma unroll
                for (int r = 0; r < 4; ++r) t[r] = fmaxf(t[r], acc[mi][nj][r]);
            }
        }
        #pragma unroll
        for (int m = 1; m <= 8; m <<= 1) {
            #pragma unroll
            for (int r = 0; r < 4; ++r) t[r] = fmaxf(t[r], __shfl_xor(t[r], m));
        }
        if (lane15 == 0) {
            int rb = wm * 64 + mi * 16 + lg * 4;
            #pragma unroll
            for (int r = 0; r < 4; ++r) red[wn][rb + r] = t[r];
        }
    }
    __syncthreads();
    if (tid < 256) {
        float vmx = fmaxf(red[0][tid], red[1][tid]);
        pmax[((size_t)l * NT + nt) * M_PAD + mt * 256 + tid] = vmx;
    }
}

// --------------------- K3: small net + fused combine + fused resize (512 thr)
__device__ __forceinline__ float block_sum8(float v, volatile float* scratch) {
    #pragma unroll
    for (int m = 32; m; m >>= 1) v += __shfl_xor(v, m);
    int w = threadIdx.x >> 6;
    __syncthreads();
    if ((threadIdx.x & 63) == 0) scratch[w] = v;
    __syncthreads();
    float r = 0.f;
    #pragma unroll
    for (int i = 0; i < 8; ++i) r += scratch[i];
    return r;
}
__device__ __forceinline__ float block_max8(float v, volatile float* scratch) {
    #pragma unroll
    for (int m = 32; m; m >>= 1) v = fmaxf(v, __shfl_xor(v, m));
    int w = threadIdx.x >> 6;
    __syncthreads();
    if ((threadIdx.x & 63) == 0) scratch[w] = v;
    __syncthreads();
    float r = scratch[0];
    #pragma unroll
    for (int i = 1; i < 8; ++i) r = fmaxf(r, scratch[i]);
    return r;
}

__global__ __launch_bounds__(512)
void k_small(const float* __restrict__ ie, const float* __restrict__ te,
             const float* __restrict__ ier,
             const float* __restrict__ a_w1, const float* __restrict__ a_w2,
             const float* __restrict__ r_w1, const float* __restrict__ r_b1,
             const float* __restrict__ r_g2, const float* __restrict__ r_be2,
             const float* __restrict__ r_w2, const float* __restrict__ r_b2,
             const float* __restrict__ r_g3, const float* __restrict__ r_be3,
             const float* __restrict__ r_w3, const float* __restrict__ r_b3,
             const float* __restrict__ h_w1, const float* __restrict__ h_b1,
             const float* __restrict__ h_g2, const float* __restrict__ h_be2,
             const float* __restrict__ h_w2, const float* __restrict__ h_b2,
             const float* __restrict__ h_g3, const float* __restrict__ h_be3,
             const float* __restrict__ h_w3, const float* __restrict__ h_b3,
             const float* __restrict__ pmax, const float* __restrict__ rnorm,
             float* __restrict__ out_score, float* __restrict__ outh)
{
    int b = blockIdx.x, tid = threadIdx.x;
    __shared__ float x[D_DIM];
    __shared__ float h1[160];
    __shared__ float dif[D_DIM];
    __shared__ float z1[128];
    __shared__ float z2[64];
    __shared__ float hol[P_DIM];
    __shared__ float rcp[P_DIM];
    __shared__ float heatl[256];
    __shared__ float scratch[8];

    for (int i = tid; i < D_DIM; i += 512) x[i] = ie[b * D_DIM + i];
    __syncthreads();

    float ss = 0.f, d0 = 0.f, d1 = 0.f;
    for (int i = tid; i < D_DIM; i += 512) {
        float v = x[i];
        ss += v * v;
        d0 += v * te[i];
        d1 += v * te[D_DIM + i];
    }
    float ssum = block_sum8(ss, scratch);
    float dd0 = block_sum8(d0, scratch);
    float dd1 = block_sum8(d1, scratch);
    float tscore = 1.f / (1.f + expf(100.f * rsqrtf(ssum) * (dd0 - dd1)));

    for (int o = tid; o < 160; o += 512) {
        const float* w = a_w1 + (size_t)o * D_DIM;
        float s0 = 0, s1 = 0, s2 = 0, s3 = 0;
        for (int d = 0; d < D_DIM; d += 4) {
            s0 += x[d] * w[d]; s1 += x[d + 1] * w[d + 1];
            s2 += x[d + 2] * w[d + 2]; s3 += x[d + 3] * w[d + 3];
        }
        h1[o] = fmaxf((s0 + s1) + (s2 + s3), 0.f);
    }
    __syncthreads();
    for (int d = tid; d < D_DIM; d += 512) {
        const float* w = a_w2 + (size_t)d * 160;
        float s0 = 0, s1 = 0, s2 = 0, s3 = 0;
        for (int o = 0; o < 160; o += 4) {
            s0 += h1[o] * w[o]; s1 += h1[o + 1] * w[o + 1];
            s2 += h1[o + 2] * w[o + 2]; s3 += h1[o + 3] * w[o + 3];
        }
        dif[d] = ier[d] - fmaxf((s0 + s1) + (s2 + s3), 0.f);
    }
    __syncthreads();

    for (int o = tid; o < 128; o += 512) {
        const float* w = r_w1 + (size_t)o * D_DIM;
        float s0 = 0, s1 = 0, s2 = 0, s3 = 0;
        for (int d = 0; d < D_DIM; d += 4) {
            s0 += dif[d] * w[d]; s1 += dif[d + 1] * w[d + 1];
            s2 += dif[d + 2] * w[d + 2]; s3 += dif[d + 3] * w[d + 3];
        }
        float s = (s0 + s1) + (s2 + s3) + r_b1[o];
        z1[o] = fmaxf(s, 0.f) * (r_g2[o] * BNSCALE) + r_be2[o];
    }
    __syncthreads();
    for (int o = tid; o < 64; o += 512) {
        const float* w = r_w2 + (size_t)o * 128;
        float s = r_b2[o];
        for (int d = 0; d < 128; ++d) s += z1[d] * w[d];
        z2[o] = fmaxf(s, 0.f) * (r_g3[o] * BNSCALE) + r_be3[o];
    }
    __syncthreads();
    float sp = (tid < 64) ? z2[tid] * r_w3[tid] : 0.f;
    float irs = 1.f / (1.f + expf(-(block_sum8(sp, scratch) + r_b3[0])));

    float fgp = -__builtin_inff();
    float base = tscore + irs;
    for (int p = tid; p < P_DIM; p += 512) {
        int r = b * P_DIM + p;
        float s = 0.f;
        #pragma unroll
        for (int l = 0; l < L_DIM; ++l) {
            float m = -__builtin_inff();
            #pragma unroll
            for (int t = 0; t < NT; ++t)
                m = fmaxf(m, pmax[((size_t)l * NT + t) * M_PAD + r]);
            s += m * rnorm[l * M_TOT + r];
        }
        float pv = (3.0f - s) / 6.0f;
        fgp = fmaxf(fgp, pv);
        float h = base + pv;
        hol[p] = h;
        rcp[p] = 1.f / h;
    }
    float fg = block_max8(fgp, scratch);

    for (int o = tid; o < 128; o += 512) {
        const float* w = h_w1 + (size_t)o * P_DIM;
        float s = h_b1[o];
        for (int d = 0; d < P_DIM; ++d) s += hol[d] * w[d];
        z1[o] = fmaxf(s, 0.f) * (h_g2[o] * BNSCALE) + h_be2[o];
    }
    __syncthreads();
    for (int o = tid; o < 64; o += 512) {
        const float* w = h_w2 + (size_t)o * 128;
        float s = h_b2[o];
        for (int d = 0; d < 128; ++d) s += z1[d] * w[d];
        z2[o] = fmaxf(s, 0.f) * (h_g3[o] * BNSCALE) + h_be3[o];
    }
    __syncthreads();
    float sp2 = (tid < 64) ? z2[tid] * h_w3[tid] : 0.f;
    float hl_in = block_sum8(sp2, scratch) + h_b3[0];
    if (tid == 0) {
        float hl = 1.f / (1.f + expf(-hl_in));
        out_score[b] = (hl + fg) * 0.5f;
    }

    if (tid < 256) {
        int r = tid >> 4, c = tid & 15;
        float s = 0.f, cnt = 0.f;
        #pragma unroll
        for (int di = -1; di <= 0; ++di) {
            int i = r + di;
            if (i < 0 || i > 14) continue;
            #pragma unroll
            for (int dj = -1; dj <= 0; ++dj) {
                int j = c + dj;
                if (j < 0 || j > 14) continue;
                s += rcp[i * 15 + j];
                cnt += 1.f;
            }
        }
        heatl[tid] = cnt / s;
    }
    __syncthreads();

    // fused resize: jax bilinear 16->240 == clamped half-pixel, s=(o-7)/15
    float* dst = outh + (size_t)b * (S_DIM * S_DIM);
    for (int px = tid; px < S_DIM * S_DIM; px += 512) {
        int y = px / S_DIM, xc = px - y * S_DIM;
        float sy = fminf(fmaxf((y - 7) * (1.0f / 15.0f), 0.f), 15.f);
        float sx = fminf(fmaxf((xc - 7) * (1.0f / 15.0f), 0.f), 15.f);
        int y0 = (int)sy, x0 = (int)sx;
        int y1 = min(y0 + 1, 15), x1 = min(x0 + 1, 15);
        float fy = sy - (float)y0, fx = sx - (float)x0;
        float v00 = heatl[y0 * 16 + x0], v01 = heatl[y0 * 16 + x1];
        float v10 = heatl[y1 * 16 + x0], v11 = heatl[y1 * 16 + x1];
        float vv = (1.f - fy) * ((1.f - fx) * v00 + fx * v01)
                 + fy * ((1.f - fx) * v10 + fx * v11);
        dst[px] = vv;
    }
}

// ---------------------------------------------------------------- launcher
extern "C" void kernel_launch(void* const* d_in, const int* in_sizes, int n_in,
                              void* d_out, int out_size, void* d_ws, size_t ws_size,
                              hipStream_t stream)
{
    (void)in_sizes; (void)n_in; (void)out_size; (void)ws_size;
    const float* image_embeds = (const float*)d_in[1];
    const float* patch_embeds = (const float*)d_in[2];
    const float* text_embeds  = (const float*)d_in[3];
    const float* ier          = (const float*)d_in[4];
    const float* per          = (const float*)d_in[5];
    const float* a_w1 = (const float*)d_in[6];
    const float* a_w2 = (const float*)d_in[7];
    const float* r_w1 = (const float*)d_in[8];
    const float* r_b1 = (const float*)d_in[9];
    const float* r_g2 = (const float*)d_in[10];
    const float* r_be2 = (const float*)d_in[11];
    const float* r_w2 = (const float*)d_in[12];
    const float* r_b2 = (const float*)d_in[13];
    const float* r_g3 = (const float*)d_in[14];
    const float* r_be3 = (const float*)d_in[15];
    const float* r_w3 = (const float*)d_in[16];
    const float* r_b3 = (const float*)d_in[17];
    const float* h_w1 = (const float*)d_in[18];
    const float* h_b1 = (const float*)d_in[19];
    const float* h_g2 = (const float*)d_in[20];
    const float* h_be2 = (const float*)d_in[21];
    const float* h_w2 = (const float*)d_in[22];
    const float* h_b2 = (const float*)d_in[23];
    const float* h_g3 = (const float*)d_in[24];
    const float* h_be3 = (const float*)d_in[25];
    const float* h_w3 = (const float*)d_in[26];
    const float* h_b3 = (const float*)d_in[27];

    char* ws = (char*)d_ws;
    size_t off = 0;
    auto take = [&](size_t bytes) -> void* {
        void* p = ws + off;
        off += (bytes + 255) & ~(size_t)255;
        return p;
    };
    float* rnorm = (float*)take((size_t)L_DIM * M_TOT * 4);            // 173 KB
    float* pmax  = (float*)take((size_t)L_DIM * NT * M_PAD * 4);       // 2.6 MB
    unsigned short* abf = (unsigned short*)take((size_t)L_DIM * M_PAD * D_DIM * 2); // 56.0 MB
    unsigned short* rbf = (unsigned short*)take((size_t)L_DIM * N_PAD * D_DIM * 2); //  7.4 MB

    float* out_f = (float*)d_out;  // [64] final_score || [64*240*240] hmap, f32

    k_convert<<<dim3((L_DIM * M_PAD + L_DIM * N_PAD) / 4), dim3(256), 0, stream>>>(
        patch_embeds, per, abf, rbf, rnorm);
    k_gemm_max<<<dim3(L_DIM * MT * NT), dim3(512), 0, stream>>>(abf, rbf, pmax);
    k_small<<<dim3(B_DIM), dim3(512), 0, stream>>>(image_embeds, text_embeds, ier,
        a_w1, a_w2, r_w1, r_b1, r_g2, r_be2, r_w2, r_b2, r_g3, r_be3, r_w3, r_b3,
        h_w1, h_b1, h_g2, h_be2, h_w2, h_b2, h_g3, h_be3, h_w3, h_b3,
        pmax, rnorm, out_f, out_f + B_DIM);
}